// Round 1
// baseline (41814.984 us; speedup 1.0000x reference)
//
#include <hip/hip_runtime.h>
#include <hip/hip_bf16.h>
#include <hip/hip_cooperative_groups.h>

#define HID   1024
#define BATCH 512
#define SEQ   256
#define OUTD  64
#define NGATE 4096
#define NBLK  256
#define NTHR  512

typedef __attribute__((ext_vector_type(8))) short bf16x8;
typedef __attribute__((ext_vector_type(4))) float f32x4;
typedef unsigned short u16;
typedef unsigned long long u64;

// dynamic LDS: xs0 [64][520] bf16 (66560 B), xs1 (66560 B), slabs 8 x 1280 B
#define XS_STRIDE 520
#define XS_BYTES  (64 * XS_STRIDE * 2)
#define LDS_BYTES (2 * XS_BYTES + 8 * 1280)

__device__ __forceinline__ u16 f2bf(float v) {
  union { float f; unsigned u; } u; u.f = v;
  unsigned r = u.u + 0x7fffu + ((u.u >> 16) & 1u);
  return (u16)(r >> 16);
}
__device__ __forceinline__ float bf2f(u16 b) {
  union { unsigned u; float f; } u; u.u = ((unsigned)b) << 16;
  return u.f;
}
__device__ __forceinline__ float sigf(float x) { return 1.0f / (1.0f + __expf(-x)); }
__device__ __forceinline__ float tanh_fast(float x) {
  float ax = fabsf(x);
  float e = __expf(-2.0f * ax);
  return copysignf((1.0f - e) / (1.0f + e), x);
}

// agent-scope relaxed atomic accessors: lower to loads/stores with sc-bits that
// bypass the (XCD-incoherent) caches -> no stale data, no fences needed.
__device__ __forceinline__ u64 ld_dev64(const u16* p) {
  return __hip_atomic_load((const u64*)p, __ATOMIC_RELAXED, __HIP_MEMORY_SCOPE_AGENT);
}
__device__ __forceinline__ void st_dev32(u16* p, unsigned v) {
  __hip_atomic_store((unsigned*)p, v, __ATOMIC_RELAXED, __HIP_MEMORY_SCOPE_AGENT);
}

// fragment-order index for W slabs: slab s=np>>4 owns gate rows [16s,16s+16).
// frag f=k>>5 (512 elems, 1KB): elem[(q*16+nl)*8+e] = W[n'=16s+nl][k=f*32+q*8+e]
__device__ __forceinline__ size_t fragidx(int np, int k) {
  int b = np >> 4, nl = np & 15;
  int f = k >> 5, q = (k >> 3) & 3, e = k & 7;
  return ((size_t)b * 64 + f) * 512 + (q * 16 + nl) * 8 + e;
}

// ---------------- prepass kernels (unchanged, verified) ----------------

__global__ void k_build_w0f(const float* __restrict__ Whh0, const float* __restrict__ Wih0,
                            const float* __restrict__ fcw, u16* __restrict__ w0f) {
  int np = blockIdx.x;
  int j = np >> 2, g = np & 3;
  int orig = g * 1024 + j;
  int tid = threadIdx.x;
  __shared__ float wrow[64];
  if (tid < 64) wrow[tid] = Wih0[orig * 64 + tid];
  __syncthreads();
  for (int k = tid; k < 1024; k += 256) {
    w0f[fragidx(np, k)] = f2bf(Whh0[(size_t)orig * 1024 + k]);
    float acc = 0.f;
#pragma unroll
    for (int o = 0; o < 64; ++o) acc += wrow[o] * fcw[o * 1024 + k];
    w0f[fragidx(np, 1024 + k)] = f2bf(acc);
  }
}

__global__ void k_build_w1f(const float* __restrict__ Wih1, const float* __restrict__ Whh1,
                            u16* __restrict__ w1f) {
  int np = blockIdx.x;
  int j = np >> 2, g = np & 3;
  int orig = g * 1024 + j;
  int tid = threadIdx.x;
  for (int k = tid; k < 1024; k += 256) {
    w1f[fragidx(np, k)]        = f2bf(Wih1[(size_t)orig * 1024 + k]);
    w1f[fragidx(np, 1024 + k)] = f2bf(Whh1[(size_t)orig * 1024 + k]);
  }
}

__global__ void k_build_bias(const float* bih0, const float* bhh0,
                             const float* bih1, const float* bhh1,
                             const float* Wih0, const float* fcb,
                             float* bias0b, float* bias0x, float* bias1) {
  int np = blockIdx.x * 256 + threadIdx.x;
  if (np >= NGATE) return;
  int j = np >> 2, g = np & 3;
  int orig = g * 1024 + j;
  bias0b[np] = bih0[orig] + bhh0[orig];
  bias1[np]  = bih1[orig] + bhh1[orig];
  float acc = 0.f;
#pragma unroll
  for (int o = 0; o < 64; ++o) acc += Wih0[orig * 64 + o] * fcb[o];
  bias0x[np] = acc;   // fc_out bias routed through W_ih0 (valid only t>=1; x(0)=0)
}

__global__ void k_fcwb(const float* __restrict__ fcw, u16* __restrict__ fcwb) {
  int idx = blockIdx.x * 256 + threadIdx.x;  // 65536
  fcwb[idx] = f2bf(fcw[idx]);
}

__global__ void k_init(const float* __restrict__ zs, const float* __restrict__ zk,
                       const float* __restrict__ fiw, const float* __restrict__ fib,
                       u16* __restrict__ xa0, u16* __restrict__ xb0) {
  int r = blockIdx.x;
  int tid = threadIdx.x;
  __shared__ float z[256];
  if (tid < 128) z[tid] = zs[r * 128 + tid];
  else           z[tid] = zk[r * 128 + (tid - 128)];
  __syncthreads();
  for (int h = tid; h < 1024; h += 256)
    xa0[(size_t)r * 2048 + 1024 + h] = 0;    // x-source at t=0 is zero
  for (int c = tid; c < 2048; c += 256) {
    float acc = fib[c];
    const float* w = fiw + (size_t)c * 256;
#pragma unroll 8
    for (int k = 0; k < 256; ++k) acc += z[k] * w[k];
    int l = (r >= 256) ? 1 : 0;
    int b = 2 * (r - l * 256) + (c >> 10);
    int h = c & 1023;
    u16 v = f2bf(acc);
    if (l == 0) xa0[(size_t)b * 2048 + h] = v;
    else        xb0[(size_t)b * 2048 + 1024 + h] = v;
  }
}

// ---------------- main cooperative kernel ----------------

struct Params {
  const u16* w0f;        // frag-ordered, 16MB (plain cached loads; L2/L3 stream)
  const u16* w1f;
  const float* bias0b;
  const float* bias0x;
  const float* bias1;
  u16* xa0; u16* xa1;    // phase-A operands [512][2048] = [h0_prev | h1_prev]
  u16* xb0; u16* xb1;    // phase-B operands [512][2048] = [h0_new  | h1_prev]
  const u16* fcwb;       // [64][1024] bf16
  const float* fcb;
  float* out;            // [512][256][64]
  unsigned* flags;       // [512 bars][8 grp][32 rank]
};

// group barrier: 32 blocks of one batch-group.
// FENCE-FREE protocol: all cross-block data moves via agent-scope relaxed
// atomics (cache-bypassing), so no buffer_wbl2/buffer_inv L2 walks are needed.
// The __syncthreads() before the flag store drains each wave's vmcnt
// (compiler-emitted s_waitcnt vmcnt(0) before s_barrier), so all data stores
// of the block are complete at the coherent point before the flag publishes.
__device__ __forceinline__ void gbar(unsigned* flags, int bar, int grp, int rank, int tid) {
  __syncthreads();   // drains vmcnt(0) for every wave -> data globally visible
  if (tid < 64) {
    unsigned* f = flags + (bar * 8 + grp) * 32;
    if (tid == 0)
      __hip_atomic_store(&f[rank], 1u, __ATOMIC_RELAXED, __HIP_MEMORY_SCOPE_AGENT);
    int sl = tid & 31;
    while (true) {
      unsigned v = __hip_atomic_load(&f[sl], __ATOMIC_RELAXED, __HIP_MEMORY_SCOPE_AGENT);
      if (__ballot(v == 1u) == ~0ull) break;
      __builtin_amdgcn_s_sleep(1);
    }
  }
  __syncthreads();
}

// gates tile [64 m x 16 n per wave] = Xgroup @ Wslab^T.
// X LDS-staged in 4 k-chunks (double-buffered) via 8B cache-bypassing loads;
// W streamed (plain, cacheable) -> regs depth-8.
__device__ __forceinline__ void gemm_phase(
    const u16* __restrict__ Xg,   // X + grp*64*2048
    const u16* __restrict__ Wp,   // wave's 64KB W slab
    u16* xs0, u16* xs1, int tid, int lane, f32x4 acc[4])
{
  const int lr = lane & 15, lq = lane >> 4;
  const int srow = tid >> 3;             // staging row 0..63
  const int scol = (tid & 7) * 64;       // staging col base (elems)

  bf16x8 w[8];
#pragma unroll
  for (int f = 0; f < 8; ++f)
    w[f] = *(const bf16x8*)(Wp + f * 512 + lane * 8);

  // stage chunk 0 (agent-scope loads: written by other blocks last phase)
#pragma unroll
  for (int i = 0; i < 16; ++i)
    *(u64*)(xs0 + srow * XS_STRIDE + scol + i * 4) =
        ld_dev64(Xg + (size_t)srow * 2048 + scol + i * 4);
  __syncthreads();

#pragma unroll
  for (int c = 0; c < 4; ++c) {
    u16* xsc = (c & 1) ? xs1 : xs0;
    u16* xsn = (c & 1) ? xs0 : xs1;
    if (c < 3) {   // stage next chunk concurrently with compute
#pragma unroll
      for (int i = 0; i < 16; ++i)
        *(u64*)(xsn + srow * XS_STRIDE + scol + i * 4) =
            ld_dev64(Xg + (size_t)srow * 2048 + (c + 1) * 512 + scol + i * 4);
    }
#pragma unroll
    for (int kf = 0; kf < 16; ++kf) {
      const int f = c * 16 + kf;
      bf16x8 wf = w[f & 7];
      if (f < 56) w[f & 7] = *(const bf16x8*)(Wp + (f + 8) * 512 + lane * 8);
      const u16* xb = xsc + lr * XS_STRIDE + kf * 32 + lq * 8;
      acc[0] = __builtin_amdgcn_mfma_f32_16x16x32_bf16(*(const bf16x8*)(xb),                  wf, acc[0], 0, 0, 0);
      acc[1] = __builtin_amdgcn_mfma_f32_16x16x32_bf16(*(const bf16x8*)(xb + 16 * XS_STRIDE), wf, acc[1], 0, 0, 0);
      acc[2] = __builtin_amdgcn_mfma_f32_16x16x32_bf16(*(const bf16x8*)(xb + 32 * XS_STRIDE), wf, acc[2], 0, 0, 0);
      acc[3] = __builtin_amdgcn_mfma_f32_16x16x32_bf16(*(const bf16x8*)(xb + 48 * XS_STRIDE), wf, acc[3], 0, 0, 0);
    }
    __syncthreads();
  }
}

// fused LSTM cell on the wave's [64 m x 16 n] gates; h dual-write.
// h values are published as packed-u32 agent-scope atomic stores (cache-
// bypassing): lane pairs (jl, jl^1) combine via shfl so the store is a
// native 4B atomic covering cols (jg, jg+1).
__device__ __forceinline__ void cell_store(
    f32x4 acc[4], float* cr, u16* __restrict__ d1, u16* __restrict__ d2,
    const float* bg, const float* bx, bool ubx,
    int grp, int jg, int lane, float* slab)
{
  const int lr = lane & 15, lq = lane >> 4;
  const int rr = lane & 3;
#pragma unroll
  for (int mf = 0; mf < 4; ++mf) {
#pragma unroll
    for (int r2 = 0; r2 < 4; ++r2)
      slab[(lq * 4 + r2) * 20 + lr] = acc[mf][r2];
    f32x4 g4 = *(f32x4*)&slab[(lq * 4 + rr) * 20 + 4 * ((lane >> 2) & 3)];
    float gi = g4[0] + bg[0] + (ubx ? bx[0] : 0.f);
    float gf = g4[1] + bg[1] + (ubx ? bx[1] : 0.f);
    float gg = g4[2] + bg[2] + (ubx ? bx[2] : 0.f);
    float go = g4[3] + bg[3] + (ubx ? bx[3] : 0.f);
    float iv = sigf(gi), fv = sigf(gf), gv = tanh_fast(gg), ov = sigf(go);
    float cnew = fv * cr[mf] + iv * gv;
    float hnew = ov * tanh_fast(cnew);
    cr[mf] = cnew;
    u16 hv = f2bf(hnew);
    unsigned other = __shfl_xor((unsigned)hv, 4);   // partner col jg^1
    int m = mf * 16 + lq * 4 + rr;
    size_t row = (size_t)(grp * 64 + m) * 2048;
    if ((lane & 4) == 0) {                          // even jl: own col is even
      unsigned pair = (unsigned)hv | (other << 16);
      st_dev32(d1 + row + jg, pair);
      st_dev32(d2 + row + jg, pair);
    }
  }
}

// out(t-1) from the staged h1 chunks (xs0 = h1 cols [0,512), xs1 = [512,1024))
__device__ __forceinline__ void out_proj_lds(const u16* xs0, const u16* xs1,
                                             const Params& p, int grp, int rank,
                                             int tid, int tq) {
  int D = rank * 128 + (tid >> 2);
  int brow = D >> 6, o = D & 63;
  int ks = tid & 3;
  const u16* h = ((ks < 2) ? xs0 : xs1) + brow * XS_STRIDE + (ks & 1) * 256;
  const u16* w = p.fcwb + (size_t)o * 1024 + ks * 256;
  float acc = 0.f;
#pragma unroll 4
  for (int kk = 0; kk < 256; kk += 8) {
    bf16x8 hv = *(const bf16x8*)(h + kk);
    bf16x8 wv = *(const bf16x8*)(w + kk);
#pragma unroll
    for (int j = 0; j < 8; ++j)
      acc += bf2f(((u16*)&hv)[j]) * bf2f(((u16*)&wv)[j]);
  }
  acc += __shfl_xor(acc, 1);
  acc += __shfl_xor(acc, 2);
  if (ks == 0)
    p.out[((size_t)(grp * 64 + brow) * SEQ + tq) * OUTD + o] = acc + p.fcb[o];
}

// final out(SEQ-1): h1 from global buffer (written by other blocks -> agent loads)
__device__ __forceinline__ void out_proj_g(const u16* __restrict__ Xsrc, const Params& p,
                                           int grp, int rank, int tid, int tq) {
  int D = rank * 128 + (tid >> 2);
  int brow = D >> 6, o = D & 63;
  int ks = tid & 3;
  const u16* h = Xsrc + (size_t)(grp * 64 + brow) * 2048 + 1024 + ks * 256;
  const u16* w = p.fcwb + (size_t)o * 1024 + ks * 256;
  float acc = 0.f;
#pragma unroll 8
  for (int kk = 0; kk < 256; kk += 4) {
    u64 hv = ld_dev64(h + kk);
    const u16* wp = w + kk;
    acc += bf2f((u16)(hv      )) * bf2f(wp[0]);
    acc += bf2f((u16)(hv >> 16)) * bf2f(wp[1]);
    acc += bf2f((u16)(hv >> 32)) * bf2f(wp[2]);
    acc += bf2f((u16)(hv >> 48)) * bf2f(wp[3]);
  }
  acc += __shfl_xor(acc, 1);
  acc += __shfl_xor(acc, 2);
  if (ks == 0)
    p.out[((size_t)(grp * 64 + brow) * SEQ + tq) * OUTD + o] = acc + p.fcb[o];
}

__global__ __launch_bounds__(NTHR, 2)
void k_lstm(Params p) {
  extern __shared__ char smem[];
  const int blk = blockIdx.x, tid = threadIdx.x;
  const int lane = tid & 63, wave = tid >> 6;
  const int grp = blk & 7;        // batch group (XCD-aligned by %8 heuristic)
  const int rank = blk >> 3;      // rank within group, 0..31

  u16* xs0 = (u16*)smem;
  u16* xs1 = (u16*)(smem + XS_BYTES);
  float* slab = (float*)(smem + 2 * XS_BYTES) + wave * 320;

  const int sid = rank * 8 + wave;     // W slab id 0..255 (16 gate rows each)
  const u16* W0p = p.w0f + (size_t)sid * 32768;
  const u16* W1p = p.w1f + (size_t)sid * 32768;
  const int jg = rank * 32 + wave * 4 + ((lane >> 2) & 3);   // lane's hidden unit

  float b0r[4], bxr[4], b1r[4];
  float c0r[4] = {0, 0, 0, 0}, c1r[4] = {0, 0, 0, 0};
#pragma unroll
  for (int g = 0; g < 4; ++g) {
    b0r[g] = p.bias0b[4 * jg + g];
    bxr[g] = p.bias0x[4 * jg + g];
    b1r[g] = p.bias1[4 * jg + g];
  }

  int bar = 0;
  for (int t = 0; t < SEQ; ++t) {
    const int pr = t & 1;
    u16* xap = pr ? p.xa1 : p.xa0;
    u16* xan = pr ? p.xa0 : p.xa1;
    u16* xbp = pr ? p.xb1 : p.xb0;
    u16* xbn = pr ? p.xb0 : p.xb1;
    // ---- phase A: gates0 = xap @ W0^T ; h0(t) -> xbp.h0 + xan.h0 ----
    {
      f32x4 acc[4] = {{0,0,0,0},{0,0,0,0},{0,0,0,0},{0,0,0,0}};
      gemm_phase(xap + (size_t)grp * 64 * 2048, W0p, xs0, xs1, tid, lane, acc);
      if (t > 0) out_proj_lds(xs0, xs1, p, grp, rank, tid, t - 1); // h1(t-1) staged
      cell_store(acc, c0r, xbp, xan, b0r, bxr, t > 0, grp, jg, lane, slab);
    }
    gbar(p.flags, bar++, grp, rank, tid);
    // ---- phase B: gates1 = xbp @ W1^T ; h1(t) -> xan.h1 + xbn.h1 ----
    {
      f32x4 acc[4] = {{0,0,0,0},{0,0,0,0},{0,0,0,0},{0,0,0,0}};
      gemm_phase(xbp + (size_t)grp * 64 * 2048, W1p, xs0, xs1, tid, lane, acc);
      cell_store(acc, c1r, xan + 1024, xbn + 1024, b1r, nullptr, false, grp, jg, lane, slab);
    }
    gbar(p.flags, bar++, grp, rank, tid);
  }
  out_proj_g(p.xa0, p, grp, rank, tid, SEQ - 1);   // h1(255) in xa0.h1
}

// ---------------- launch ----------------

extern "C" void kernel_launch(void* const* d_in, const int* in_sizes, int n_in,
                              void* d_out, int out_size, void* d_ws, size_t ws_size,
                              hipStream_t stream) {
  const float* zs   = (const float*)d_in[0];
  const float* zk   = (const float*)d_in[1];
  const float* fiw  = (const float*)d_in[2];
  const float* fib  = (const float*)d_in[3];
  const float* Wih0 = (const float*)d_in[4];
  const float* Whh0 = (const float*)d_in[5];
  const float* bih0 = (const float*)d_in[6];
  const float* bhh0 = (const float*)d_in[7];
  const float* Wih1 = (const float*)d_in[8];
  const float* Whh1 = (const float*)d_in[9];
  const float* bih1 = (const float*)d_in[10];
  const float* bhh1 = (const float*)d_in[11];
  const float* fcw  = (const float*)d_in[12];
  const float* fcb  = (const float*)d_in[13];
  float* out = (float*)d_out;

  char* ws = (char*)d_ws;
  size_t off = 0;
  auto alloc = [&](size_t bytes) -> char* {
    char* pp = ws + off;
    off += (bytes + 255) & ~(size_t)255;
    return pp;
  };
  u16* w0f  = (u16*)alloc((size_t)NGATE * 2048 * 2);
  u16* w1f  = (u16*)alloc((size_t)NGATE * 2048 * 2);
  u16* xa0  = (u16*)alloc((size_t)BATCH * 2048 * 2);
  u16* xa1  = (u16*)alloc((size_t)BATCH * 2048 * 2);
  u16* xb0  = (u16*)alloc((size_t)BATCH * 2048 * 2);
  u16* xb1  = (u16*)alloc((size_t)BATCH * 2048 * 2);
  u16* fcwb = (u16*)alloc((size_t)OUTD * HID * 2);
  float* bias0b = (float*)alloc(NGATE * 4);
  float* bias0x = (float*)alloc(NGATE * 4);
  float* bias1  = (float*)alloc(NGATE * 4);
  unsigned* flags = (unsigned*)alloc((size_t)2 * SEQ * 8 * 32 * 4);

  hipMemsetAsync(flags, 0, (size_t)2 * SEQ * 8 * 32 * 4, stream);

  hipLaunchKernelGGL(k_build_w0f, dim3(NGATE), dim3(256), 0, stream, Whh0, Wih0, fcw, w0f);
  hipLaunchKernelGGL(k_build_w1f, dim3(NGATE), dim3(256), 0, stream, Wih1, Whh1, w1f);
  hipLaunchKernelGGL(k_build_bias, dim3(16), dim3(256), 0, stream,
                     bih0, bhh0, bih1, bhh1, Wih0, fcb, bias0b, bias0x, bias1);
  hipLaunchKernelGGL(k_fcwb, dim3(256), dim3(256), 0, stream, fcw, fcwb);
  hipLaunchKernelGGL(k_init, dim3(BATCH), dim3(256), 0, stream, zs, zk, fiw, fib, xa0, xb0);

  Params prm;
  prm.w0f = w0f; prm.w1f = w1f;
  prm.bias0b = bias0b; prm.bias0x = bias0x; prm.bias1 = bias1;
  prm.xa0 = xa0; prm.xa1 = xa1; prm.xb0 = xb0; prm.xb1 = xb1;
  prm.fcwb = fcwb; prm.fcb = fcb; prm.out = out;
  prm.flags = flags;

  hipFuncSetAttribute((const void*)k_lstm, hipFuncAttributeMaxDynamicSharedMemorySize, LDS_BYTES);
  void* args[] = { &prm };
  hipLaunchCooperativeKernel((void*)k_lstm, dim3(NBLK), dim3(NTHR), args, LDS_BYTES, stream);
}

// Round 2
// 32725.665 us; speedup vs baseline: 1.2777x; 1.2777x over previous
//
#include <hip/hip_runtime.h>
#include <hip/hip_bf16.h>
#include <hip/hip_cooperative_groups.h>

#define HID   1024
#define BATCH 512
#define SEQ   256
#define OUTD  64
#define NGATE 4096
#define NBLK  256
#define NTHR  512
#define GPB   2     // batch groups (256 rows each)
#define SPB   128   // blocks per group

typedef __attribute__((ext_vector_type(8))) short bf16x8;
typedef __attribute__((ext_vector_type(4))) float f32x4;
typedef __attribute__((ext_vector_type(16))) float f32x16;
typedef unsigned short u16;

// LDS: win0/win1 [64 rows][256 k] bf16 (32 KB each, XOR-swizzled), pld [8][64][32] f32 (64 KB)
#define WIN_BYTES 32768
#define LDS_BYTES (2 * WIN_BYTES + 65536)

__device__ __forceinline__ u16 f2bf(float v) {
  union { float f; unsigned u; } u; u.f = v;
  unsigned r = u.u + 0x7fffu + ((u.u >> 16) & 1u);
  return (u16)(r >> 16);
}
__device__ __forceinline__ float bf2f(u16 b) {
  union { unsigned u; float f; } u; u.u = ((unsigned)b) << 16;
  return u.f;
}
__device__ __forceinline__ float sigf(float x) { return 1.0f / (1.0f + __expf(-x)); }
__device__ __forceinline__ float tanh_fast(float x) {
  float ax = fabsf(x);
  float e = __expf(-2.0f * ax);
  return copysignf((1.0f - e) / (1.0f + e), x);
}

// agent-scope relaxed store: write-through past the (XCD-incoherent) L2 to the
// coherent point. No dirty L2 lines -> no release-wbl2 needed anywhere.
__device__ __forceinline__ void st_dev32(u16* p, unsigned v) {
  __hip_atomic_store((unsigned*)p, v, __ATOMIC_RELAXED, __HIP_MEMORY_SCOPE_AGENT);
}

// W frag index for the register-resident layout.
// np in [0,4096): s = np>>5 (block), nl = np&31 (MFMA n-col). k in [0,2048):
//   c   = k>>8      window (8 x 256 cols)
//   kq  = (k>>5)&7  wave (K split 8-ways, 32-col stripes per window)
//   kfs = (k>>4)&1  frag half (MFMA K=16)
//   h   = (k>>3)&1  lane group (lane>>5)
//   e   = k&7
// frag f = c*2+kfs holds W[np=32s+nl][k], lane l=(h*32+nl) elem e -> 16B/lane.
__device__ __forceinline__ size_t fidx(int np, int k) {
  int s = np >> 5, nl = np & 31;
  int c = k >> 8;
  int kq = (k >> 5) & 7;
  int kfs = (k >> 4) & 1;
  int h = (k >> 3) & 1;
  int e = k & 7;
  int f = c * 2 + kfs;
  return ((size_t)(s * 8 + kq) * 16 + f) * 512 + (h * 32 + nl) * 8 + e;
}

// ---------------- prepass kernels ----------------

__global__ void k_build_w0f(const float* __restrict__ Whh0, const float* __restrict__ Wih0,
                            const float* __restrict__ fcw, u16* __restrict__ w0f) {
  int np = blockIdx.x;
  int j = np >> 2, gg = np & 3;
  int orig = gg * 1024 + j;
  int tid = threadIdx.x;
  __shared__ float wrow[64];
  if (tid < 64) wrow[tid] = Wih0[orig * 64 + tid];
  __syncthreads();
  for (int k = tid; k < 1024; k += 256) {
    w0f[fidx(np, k)] = f2bf(Whh0[(size_t)orig * 1024 + k]);
    float acc = 0.f;
#pragma unroll
    for (int o = 0; o < 64; ++o) acc += wrow[o] * fcw[o * 1024 + k];
    w0f[fidx(np, 1024 + k)] = f2bf(acc);   // folded Wih0 @ fc_out
  }
}

__global__ void k_build_w1f(const float* __restrict__ Wih1, const float* __restrict__ Whh1,
                            u16* __restrict__ w1f) {
  int np = blockIdx.x;
  int j = np >> 2, gg = np & 3;
  int orig = gg * 1024 + j;
  int tid = threadIdx.x;
  for (int k = tid; k < 1024; k += 256) {
    w1f[fidx(np, k)]        = f2bf(Wih1[(size_t)orig * 1024 + k]);
    w1f[fidx(np, 1024 + k)] = f2bf(Whh1[(size_t)orig * 1024 + k]);
  }
}

__global__ void k_build_bias(const float* bih0, const float* bhh0,
                             const float* bih1, const float* bhh1,
                             const float* Wih0, const float* fcb,
                             float* bias0b, float* bias0x, float* bias1) {
  int np = blockIdx.x * 256 + threadIdx.x;
  if (np >= NGATE) return;
  int j = np >> 2, gg = np & 3;
  int orig = gg * 1024 + j;
  bias0b[np] = bih0[orig] + bhh0[orig];
  bias1[np]  = bih1[orig] + bhh1[orig];
  float acc = 0.f;
#pragma unroll
  for (int o = 0; o < 64; ++o) acc += Wih0[orig * 64 + o] * fcb[o];
  bias0x[np] = acc;   // fc_out bias routed through W_ih0 (valid only t>=1; x(0)=0)
}

__global__ void k_fcwb(const float* __restrict__ fcw, u16* __restrict__ fcwb) {
  int idx = blockIdx.x * 256 + threadIdx.x;  // 65536
  fcwb[idx] = f2bf(fcw[idx]);
}

__global__ void k_init(const float* __restrict__ zs, const float* __restrict__ zk,
                       const float* __restrict__ fiw, const float* __restrict__ fib,
                       u16* __restrict__ xa0, u16* __restrict__ xb0) {
  int r = blockIdx.x;
  int tid = threadIdx.x;
  __shared__ float z[256];
  if (tid < 128) z[tid] = zs[r * 128 + tid];
  else           z[tid] = zk[r * 128 + (tid - 128)];
  __syncthreads();
  for (int h = tid; h < 1024; h += 256)
    xa0[(size_t)r * 2048 + 1024 + h] = 0;    // x-source at t=0 is zero
  for (int c = tid; c < 2048; c += 256) {
    float acc = fib[c];
    const float* w = fiw + (size_t)c * 256;
#pragma unroll 8
    for (int k = 0; k < 256; ++k) acc += z[k] * w[k];
    int l = (r >= 256) ? 1 : 0;
    int b = 2 * (r - l * 256) + (c >> 10);
    int h = c & 1023;
    u16 v = f2bf(acc);
    if (l == 0) xa0[(size_t)b * 2048 + h] = v;
    else        xb0[(size_t)b * 2048 + 1024 + h] = v;
  }
}

// ---------------- main cooperative kernel ----------------

struct Params {
  const u16* w0f;        // frag-ordered for register residency (16 MB, read once)
  const u16* w1f;
  const float* bias0b;
  const float* bias0x;
  const float* bias1;
  u16* xa0; u16* xa1;    // phase-A operands [512][2048] = [h0_prev | h1_prev]
  u16* xb0; u16* xb1;    // phase-B operands [512][2048] = [h0_new  | h1_prev]
  const u16* fcwb;       // [64][1024] bf16
  const float* fcb;
  float* out;            // [512][256][64]
  unsigned* flags;       // [512 bars][2 grp][128 rank]
};

__global__ __launch_bounds__(NTHR, 2)
void k_lstm(Params p) {
  extern __shared__ char smem[];
  u16* win0 = (u16*)smem;                       // [64][256] bf16, swizzled
  u16* win1 = (u16*)(smem + WIN_BYTES);
  float* pld = (float*)(smem + 2 * WIN_BYTES);  // [8 kq][64 m][32 n] f32

  const int blk = blockIdx.x, tid = threadIdx.x;
  const int lane = tid & 63, wave = tid >> 6;   // wave id = kq (K-slice)
  // g clustered per-XCD-half (heuristic %8 XCD mapping, perf-only):
  const int x8 = blk & 7;
  const int g = x8 >> 2;                        // batch group 0..1
  const int s = (blk >> 3) * 4 + (x8 & 3);      // gate-slab 0..127 (np 32s..32s+32)
  const int nl = lane & 31, hh = lane >> 5;

  // ---- load W into registers: 128 VGPRs/lane, zero W fetch for all 512 phases ----
  bf16x8 w0r[16], w1r[16];
  {
    const u16* W0p = p.w0f + (size_t)(s * 8 + wave) * 8192 + (hh * 32 + nl) * 8;
    const u16* W1p = p.w1f + (size_t)(s * 8 + wave) * 8192 + (hh * 32 + nl) * 8;
#pragma unroll
    for (int f = 0; f < 16; ++f) {
      w0r[f] = *(const bf16x8*)(W0p + f * 512);
      w1r[f] = *(const bf16x8*)(W1p + f * 512);
    }
  }

  // cell assignment: one (row-in-pass, hidden-unit) per lane
  const int cr_ = tid >> 3, cj = tid & 7;
  const int npb = s * 32 + 4 * cj;
  const f32x4 b0 = *(const f32x4*)&p.bias0b[npb];
  const f32x4 bx = *(const f32x4*)&p.bias0x[npb];
  const f32x4 b1 = *(const f32x4*)&p.bias1[npb];
  const int jcol = s * 8 + cj;                  // hidden-unit column [0,1024)

  float c0s[4] = {0, 0, 0, 0}, c1s[4] = {0, 0, 0, 0};

  // group barrier over 128 blocks; relaxed flags (write-through), acquire-inv
  // (buffer_inv: L1+L2 tag drop, no data movement, nothing valuable cached).
  auto gbar = [&](int bar) {
    __syncthreads();   // drains vmcnt -> all h-stores durable at coherent point
    if (tid < SPB) {
      unsigned* f = p.flags + ((size_t)bar * GPB + g) * SPB;
      if (tid == 0)
        __hip_atomic_store(&f[s], 1u, __ATOMIC_RELAXED, __HIP_MEMORY_SCOPE_AGENT);
      while (true) {
        unsigned v = __hip_atomic_load(&f[tid], __ATOMIC_RELAXED, __HIP_MEMORY_SCOPE_AGENT);
        if (__ballot(v == 1u) == ~0ull) break;
        __builtin_amdgcn_s_sleep(1);
      }
    }
    __syncthreads();
    if (tid == 0) __builtin_amdgcn_fence(__ATOMIC_ACQUIRE, "agent");
    __syncthreads();
  };

  // out(tq) for this block's 2 batch rows, from xsrc.h1 (global, post-inv fresh)
  auto out_proj = [&](const u16* xsrc, int tq) {
    const int o = tid >> 3, ks = tid & 7;
    const int r0 = g * 256 + 2 * s;
#pragma unroll
    for (int rr = 0; rr < 2; ++rr) {
      const int r = r0 + rr;
      const u16* hp = xsrc + (size_t)r * 2048 + 1024 + ks * 128;
      const u16* wp = p.fcwb + (size_t)o * 1024 + ks * 128;
      float a = 0.f;
#pragma unroll
      for (int kk = 0; kk < 128; kk += 8) {
        bf16x8 hv = *(const bf16x8*)(hp + kk);
        bf16x8 wv = *(const bf16x8*)(wp + kk);
#pragma unroll
        for (int jj = 0; jj < 8; ++jj)
          a += bf2f(((u16*)&hv)[jj]) * bf2f(((u16*)&wv)[jj]);
      }
      a += __shfl_xor(a, 1);
      a += __shfl_xor(a, 2);
      a += __shfl_xor(a, 4);
      if (ks == 0)
        p.out[((size_t)r * SEQ + tq) * OUTD + o] = a + p.fcb[o];
    }
  };

  // one layer-phase: 4 passes of 64 batch rows; per pass: 8 double-buffered
  // X windows [64][256] (XOR-swizzled, conflict-free), 32x32x16 MFMA vs
  // register W, 8-way K-partial reduce through LDS, fused cell, h dual-publish.
  auto phase = [&](auto& wr, const u16* xsrc, u16* d1, u16* d2, int off,
                   f32x4 bb, f32x4 bxx, bool ubx, float (&cs)[4]) {
#pragma unroll
    for (int pass = 0; pass < 4; ++pass) {
      const u16* Xb = xsrc + (size_t)(g * 256 + pass * 64) * 2048;
      f32x16 acc0, acc1;
#pragma unroll
      for (int z = 0; z < 16; ++z) { acc0[z] = 0.f; acc1[z] = 0.f; }

      {  // stage window 0
        const int row = tid >> 3, seg = tid & 7, sw = (row & 7) << 4;
        const u16* src = Xb + (size_t)row * 2048 + seg * 8;
#pragma unroll
        for (int i = 0; i < 4; ++i)
          *(bf16x8*)(win0 + row * 256 + (((seg * 16 + i * 128) ^ sw) >> 1)) =
              *(const bf16x8*)(src + i * 64);
      }
      __syncthreads();
#pragma unroll
      for (int c = 0; c < 8; ++c) {
        u16* cur = (c & 1) ? win1 : win0;
        u16* nxt = (c & 1) ? win0 : win1;
        if (c < 7) {   // stage next window while computing current
          const int row = tid >> 3, seg = tid & 7, sw = (row & 7) << 4;
          const u16* src = Xb + (size_t)row * 2048 + (c + 1) * 256 + seg * 8;
#pragma unroll
          for (int i = 0; i < 4; ++i)
            *(bf16x8*)(nxt + row * 256 + (((seg * 16 + i * 128) ^ sw) >> 1)) =
                *(const bf16x8*)(src + i * 64);
        }
#pragma unroll
        for (int kfs = 0; kfs < 2; ++kfs) {
          const bf16x8 wf = wr[c * 2 + kfs];
          const int bo = wave * 64 + kfs * 32 + hh * 16;
          {
            const int row = nl;
            const bf16x8 a =
                *(const bf16x8*)(cur + row * 256 + ((bo ^ ((row & 7) << 4)) >> 1));
            acc0 = __builtin_amdgcn_mfma_f32_32x32x16_bf16(a, wf, acc0, 0, 0, 0);
          }
          {
            const int row = 32 + nl;
            const bf16x8 a =
                *(const bf16x8*)(cur + row * 256 + ((bo ^ ((row & 7) << 4)) >> 1));
            acc1 = __builtin_amdgcn_mfma_f32_32x32x16_bf16(a, wf, acc1, 0, 0, 0);
          }
        }
        __syncthreads();
      }
      // K-partials to LDS (C/D: col=lane&31, row=(reg&3)+8*(reg>>2)+4*(lane>>5))
#pragma unroll
      for (int r16 = 0; r16 < 16; ++r16) {
        const int row0 = (r16 & 3) + 8 * (r16 >> 2) + 4 * hh;
        pld[(wave * 64 + row0) * 32 + nl] = acc0[r16];
        pld[(wave * 64 + 32 + row0) * 32 + nl] = acc1[r16];
      }
      __syncthreads();
      // reduce 8 partials + cell for this lane's (row, hidden unit)
      f32x4 gs = {0.f, 0.f, 0.f, 0.f};
#pragma unroll
      for (int q = 0; q < 8; ++q) {
        const f32x4 v = *(const f32x4*)&pld[(q * 64 + cr_) * 32 + 4 * cj];
        gs[0] += v[0]; gs[1] += v[1]; gs[2] += v[2]; gs[3] += v[3];
      }
      const float gi = gs[0] + bb[0] + (ubx ? bxx[0] : 0.f);
      const float gf = gs[1] + bb[1] + (ubx ? bxx[1] : 0.f);
      const float gg = gs[2] + bb[2] + (ubx ? bxx[2] : 0.f);
      const float go = gs[3] + bb[3] + (ubx ? bxx[3] : 0.f);
      const float iv = sigf(gi), fv = sigf(gf), gv = tanh_fast(gg), ov = sigf(go);
      const float cnew = fv * cs[pass] + iv * gv;
      cs[pass] = cnew;
      const float hnew = ov * tanh_fast(cnew);
      const u16 hv = f2bf(hnew);
      const unsigned other = __shfl_xor((unsigned)hv, 1);
      if (!(tid & 1)) {   // even lane packs (jcol, jcol+1) -> one u32 store x2 dests
        const unsigned pairv = (unsigned)hv | (other << 16);
        const size_t ro = (size_t)(g * 256 + pass * 64 + cr_) * 2048 + off + jcol;
        st_dev32(d1 + ro, pairv);
        st_dev32(d2 + ro, pairv);
      }
    }
  };

  int bar = 0;
  for (int t = 0; t < SEQ; ++t) {
    u16* xap = (t & 1) ? p.xa1 : p.xa0;
    u16* xan = (t & 1) ? p.xa0 : p.xa1;
    u16* xbp = (t & 1) ? p.xb1 : p.xb0;
    u16* xbn = (t & 1) ? p.xb0 : p.xb1;
    // ---- phase A: gates0 = xap @ W0^T ; h0(t) -> xbp.h0 + xan.h0 ----
    if (t > 0) out_proj(xap, t - 1);            // out(t-1) from h1(t-1) = xap.h1
    phase(w0r, xap, xbp, xan, 0, b0, bx, t > 0, c0s);
    gbar(bar++);
    // ---- phase B: gates1 = xbp @ W1^T ; h1(t) -> xan.h1 + xbn.h1 ----
    phase(w1r, xbp, xan, xbn, 1024, b1, b1, false, c1s);
    gbar(bar++);
  }
  out_proj(p.xa0, SEQ - 1);                     // h1(255) in xa0.h1
}

// ---------------- launch ----------------

extern "C" void kernel_launch(void* const* d_in, const int* in_sizes, int n_in,
                              void* d_out, int out_size, void* d_ws, size_t ws_size,
                              hipStream_t stream) {
  const float* zs   = (const float*)d_in[0];
  const float* zk   = (const float*)d_in[1];
  const float* fiw  = (const float*)d_in[2];
  const float* fib  = (const float*)d_in[3];
  const float* Wih0 = (const float*)d_in[4];
  const float* Whh0 = (const float*)d_in[5];
  const float* bih0 = (const float*)d_in[6];
  const float* bhh0 = (const float*)d_in[7];
  const float* Wih1 = (const float*)d_in[8];
  const float* Whh1 = (const float*)d_in[9];
  const float* bih1 = (const float*)d_in[10];
  const float* bhh1 = (const float*)d_in[11];
  const float* fcw  = (const float*)d_in[12];
  const float* fcb  = (const float*)d_in[13];
  float* out = (float*)d_out;

  char* ws = (char*)d_ws;
  size_t off = 0;
  auto alloc = [&](size_t bytes) -> char* {
    char* pp = ws + off;
    off += (bytes + 255) & ~(size_t)255;
    return pp;
  };
  u16* w0f  = (u16*)alloc((size_t)NGATE * 2048 * 2);
  u16* w1f  = (u16*)alloc((size_t)NGATE * 2048 * 2);
  u16* xa0  = (u16*)alloc((size_t)BATCH * 2048 * 2);
  u16* xa1  = (u16*)alloc((size_t)BATCH * 2048 * 2);
  u16* xb0  = (u16*)alloc((size_t)BATCH * 2048 * 2);
  u16* xb1  = (u16*)alloc((size_t)BATCH * 2048 * 2);
  u16* fcwb = (u16*)alloc((size_t)OUTD * HID * 2);
  float* bias0b = (float*)alloc(NGATE * 4);
  float* bias0x = (float*)alloc(NGATE * 4);
  float* bias1  = (float*)alloc(NGATE * 4);
  unsigned* flags = (unsigned*)alloc((size_t)2 * SEQ * GPB * SPB * 4);

  hipMemsetAsync(flags, 0, (size_t)2 * SEQ * GPB * SPB * 4, stream);

  hipLaunchKernelGGL(k_build_w0f, dim3(NGATE), dim3(256), 0, stream, Whh0, Wih0, fcw, w0f);
  hipLaunchKernelGGL(k_build_w1f, dim3(NGATE), dim3(256), 0, stream, Wih1, Whh1, w1f);
  hipLaunchKernelGGL(k_build_bias, dim3(16), dim3(256), 0, stream,
                     bih0, bhh0, bih1, bhh1, Wih0, fcb, bias0b, bias0x, bias1);
  hipLaunchKernelGGL(k_fcwb, dim3(256), dim3(256), 0, stream, fcw, fcwb);
  hipLaunchKernelGGL(k_init, dim3(BATCH), dim3(256), 0, stream, zs, zk, fiw, fib, xa0, xb0);

  Params prm;
  prm.w0f = w0f; prm.w1f = w1f;
  prm.bias0b = bias0b; prm.bias0x = bias0x; prm.bias1 = bias1;
  prm.xa0 = xa0; prm.xa1 = xa1; prm.xb0 = xb0; prm.xb1 = xb1;
  prm.fcwb = fcwb; prm.fcb = fcb; prm.out = out;
  prm.flags = flags;

  hipFuncSetAttribute((const void*)k_lstm, hipFuncAttributeMaxDynamicSharedMemorySize, LDS_BYTES);
  void* args[] = { &prm };
  hipLaunchCooperativeKernel((void*)k_lstm, dim3(NBLK), dim3(NTHR), args, LDS_BYTES, stream);
}

// Round 3
// 31973.163 us; speedup vs baseline: 1.3078x; 1.0235x over previous
//
#include <hip/hip_runtime.h>
#include <hip/hip_bf16.h>
#include <hip/hip_cooperative_groups.h>

#define HID   1024
#define BATCH 512
#define SEQ   256
#define OUTD  64
#define NGATE 4096
#define NBLK  256
#define NTHR  512
#define GPB   2     // batch groups (256 rows each)
#define SPB   128   // blocks per group
#define NBAR  (2 * SEQ)

typedef __attribute__((ext_vector_type(8))) short bf16x8;
typedef __attribute__((ext_vector_type(4))) float f32x4;
typedef __attribute__((ext_vector_type(16))) float f32x16;
typedef unsigned short u16;

// LDS: win0/win1 [64 rows][256 k] bf16 (32 KB each, XOR-swizzled), pld [8][64][32] f32 (64 KB)
#define WIN_BYTES 32768
#define LDS_BYTES (2 * WIN_BYTES + 65536)

__device__ __forceinline__ u16 f2bf(float v) {
  union { float f; unsigned u; } u; u.f = v;
  unsigned r = u.u + 0x7fffu + ((u.u >> 16) & 1u);
  return (u16)(r >> 16);
}
__device__ __forceinline__ float bf2f(u16 b) {
  union { unsigned u; float f; } u; u.u = ((unsigned)b) << 16;
  return u.f;
}
__device__ __forceinline__ float sigf(float x) { return 1.0f / (1.0f + __expf(-x)); }
__device__ __forceinline__ float tanh_fast(float x) {
  float ax = fabsf(x);
  float e = __expf(-2.0f * ax);
  return copysignf((1.0f - e) / (1.0f + e), x);
}

// agent-scope relaxed store: write-through past the (XCD-incoherent) L2 to the
// coherent point (MALL). No dirty L2 lines anywhere -> release = vmcnt drain only.
__device__ __forceinline__ void st_dev32(u16* p, unsigned v) {
  __hip_atomic_store((unsigned*)p, v, __ATOMIC_RELAXED, __HIP_MEMORY_SCOPE_AGENT);
}

// W frag index for the register-resident layout.
// np in [0,4096): s = np>>5 (block), nl = np&31 (MFMA n-col). k in [0,2048):
//   c   = k>>8      window (8 x 256 cols)
//   kq  = (k>>5)&7  wave (K split 8-ways, 32-col stripes per window)
//   kfs = (k>>4)&1  frag half (MFMA K=16)
//   h   = (k>>3)&1  lane group (lane>>5)
//   e   = k&7
// frag f = c*2+kfs holds W[np=32s+nl][k], lane l=(h*32+nl) elem e -> 16B/lane.
__device__ __forceinline__ size_t fidx(int np, int k) {
  int s = np >> 5, nl = np & 31;
  int c = k >> 8;
  int kq = (k >> 5) & 7;
  int kfs = (k >> 4) & 1;
  int h = (k >> 3) & 1;
  int e = k & 7;
  int f = c * 2 + kfs;
  return ((size_t)(s * 8 + kq) * 16 + f) * 512 + (h * 32 + nl) * 8 + e;
}

// ---------------- prepass kernels ----------------

__global__ void k_build_w0f(const float* __restrict__ Whh0, const float* __restrict__ Wih0,
                            const float* __restrict__ fcw, u16* __restrict__ w0f) {
  int np = blockIdx.x;
  int j = np >> 2, gg = np & 3;
  int orig = gg * 1024 + j;
  int tid = threadIdx.x;
  __shared__ float wrow[64];
  if (tid < 64) wrow[tid] = Wih0[orig * 64 + tid];
  __syncthreads();
  for (int k = tid; k < 1024; k += 256) {
    w0f[fidx(np, k)] = f2bf(Whh0[(size_t)orig * 1024 + k]);
    float acc = 0.f;
#pragma unroll
    for (int o = 0; o < 64; ++o) acc += wrow[o] * fcw[o * 1024 + k];
    w0f[fidx(np, 1024 + k)] = f2bf(acc);   // folded Wih0 @ fc_out
  }
}

__global__ void k_build_w1f(const float* __restrict__ Wih1, const float* __restrict__ Whh1,
                            u16* __restrict__ w1f) {
  int np = blockIdx.x;
  int j = np >> 2, gg = np & 3;
  int orig = gg * 1024 + j;
  int tid = threadIdx.x;
  for (int k = tid; k < 1024; k += 256) {
    w1f[fidx(np, k)]        = f2bf(Wih1[(size_t)orig * 1024 + k]);
    w1f[fidx(np, 1024 + k)] = f2bf(Whh1[(size_t)orig * 1024 + k]);
  }
}

__global__ void k_build_bias(const float* bih0, const float* bhh0,
                             const float* bih1, const float* bhh1,
                             const float* Wih0, const float* fcb,
                             float* bias0b, float* bias0x, float* bias1) {
  int np = blockIdx.x * 256 + threadIdx.x;
  if (np >= NGATE) return;
  int j = np >> 2, gg = np & 3;
  int orig = gg * 1024 + j;
  bias0b[np] = bih0[orig] + bhh0[orig];
  bias1[np]  = bih1[orig] + bhh1[orig];
  float acc = 0.f;
#pragma unroll
  for (int o = 0; o < 64; ++o) acc += Wih0[orig * 64 + o] * fcb[o];
  bias0x[np] = acc;   // fc_out bias routed through W_ih0 (valid only t>=1; x(0)=0)
}

__global__ void k_fcwb(const float* __restrict__ fcw, u16* __restrict__ fcwb) {
  int idx = blockIdx.x * 256 + threadIdx.x;  // 65536
  fcwb[idx] = f2bf(fcw[idx]);
}

__global__ void k_init(const float* __restrict__ zs, const float* __restrict__ zk,
                       const float* __restrict__ fiw, const float* __restrict__ fib,
                       u16* __restrict__ xa0, u16* __restrict__ xb0) {
  int r = blockIdx.x;
  int tid = threadIdx.x;
  __shared__ float z[256];
  if (tid < 128) z[tid] = zs[r * 128 + tid];
  else           z[tid] = zk[r * 128 + (tid - 128)];
  __syncthreads();
  for (int h = tid; h < 1024; h += 256)
    xa0[(size_t)r * 2048 + 1024 + h] = 0;    // x-source at t=0 is zero
  for (int c = tid; c < 2048; c += 256) {
    float acc = fib[c];
    const float* w = fiw + (size_t)c * 256;
#pragma unroll 8
    for (int k = 0; k < 256; ++k) acc += z[k] * w[k];
    int l = (r >= 256) ? 1 : 0;
    int b = 2 * (r - l * 256) + (c >> 10);
    int h = c & 1023;
    u16 v = f2bf(acc);
    if (l == 0) xa0[(size_t)b * 2048 + h] = v;
    else        xb0[(size_t)b * 2048 + 1024 + h] = v;
  }
}

// ---------------- main cooperative kernel ----------------

struct Params {
  const u16* w0f;        // frag-ordered for register residency (16 MB, read once)
  const u16* w1f;
  const float* bias0b;
  const float* bias0x;
  const float* bias1;
  u16* xa0; u16* xa1;    // phase-A operands [512][2048] = [h0_prev | h1_prev]
  u16* xb0; u16* xb1;    // phase-B operands [512][2048] = [h0_new  | h1_prev]
  const u16* fcwb;       // [64][1024] bf16
  const float* fcb;
  float* out;            // [512][256][64]
  unsigned* ctr;         // [NBAR] global arrival counters
  unsigned* bclaim;      // [NBAR][8] per-XCD invalidate-duty claim
  unsigned* bdone;       // [NBAR][8] per-XCD invalidate-done flags
};

__global__ __launch_bounds__(NTHR, 2)
void k_lstm(Params p) {
  extern __shared__ char smem[];
  u16* win0 = (u16*)smem;                       // [64][256] bf16, swizzled
  u16* win1 = (u16*)(smem + WIN_BYTES);
  float* pld = (float*)(smem + 2 * WIN_BYTES);  // [8 kq][64 m][32 n] f32

  const int blk = blockIdx.x, tid = threadIdx.x;
  const int lane = tid & 63, wave = tid >> 6;   // wave id = kq (K-slice)
  const int x8 = blk & 7;
  const int g = x8 >> 2;                        // batch group 0..1
  const int s = (blk >> 3) * 4 + (x8 & 3);      // gate-slab 0..127 (np 32s..32s+32)
  const int nl = lane & 31, hh = lane >> 5;

  // physical XCD id (HW-verified on MI355X: s_getreg(HW_REG_XCC_ID) -> 0..7).
  // Used ONLY to dedupe L2 invalidates per physical L2 domain - correct for any
  // block->XCD dispatch mapping since the id is read from hardware.
  unsigned xcd;
  asm("s_getreg_b32 %0, hwreg(HW_REG_XCC_ID, 0, 32)" : "=s"(xcd));
  xcd &= 7;

  // ---- load W into registers: 128 VGPRs/lane, zero W fetch for all 512 phases ----
  bf16x8 w0r[16], w1r[16];
  {
    const u16* W0p = p.w0f + (size_t)(s * 8 + wave) * 8192 + (hh * 32 + nl) * 8;
    const u16* W1p = p.w1f + (size_t)(s * 8 + wave) * 8192 + (hh * 32 + nl) * 8;
#pragma unroll
    for (int f = 0; f < 16; ++f) {
      w0r[f] = *(const bf16x8*)(W0p + f * 512);
      w1r[f] = *(const bf16x8*)(W1p + f * 512);
    }
  }

  // cell assignment: one (row-in-pass, hidden-unit) per lane
  const int cr_ = tid >> 3, cj = tid & 7;
  const int npb = s * 32 + 4 * cj;
  const f32x4 b0 = *(const f32x4*)&p.bias0b[npb];
  const f32x4 bx = *(const f32x4*)&p.bias0x[npb];
  const f32x4 b1 = *(const f32x4*)&p.bias1[npb];
  const int jcol = s * 8 + cj;                  // hidden-unit column [0,1024)

  float c0s[4] = {0, 0, 0, 0}, c1s[4] = {0, 0, 0, 0};

  // ---- storm-free group barrier ----
  // arrival: 1 atomicAdd per block (tid0); release: 1-lane backoff poll.
  // coherence: FIRST block per physical XCD performs the (expensive) agent
  // acquire = L1+L2 invalidate, publishes done; remaining blocks on that XCD
  // flash only their private L1 (buffer_inv sc0). h-stores are write-through
  // (no dirty L2 anywhere), and __syncthreads' vmcnt(0) drain before the
  // arrival add gives release ordering - same protocol proven in prior rounds.
  auto gbar = [&](int bar) {
    __syncthreads();   // all waves drained vmcnt -> h-stores durable at MALL
    if (tid == 0) {
      __hip_atomic_fetch_add(&p.ctr[bar], 1u, __ATOMIC_RELAXED, __HIP_MEMORY_SCOPE_AGENT);
      unsigned cl = __hip_atomic_fetch_add(&p.bclaim[bar * 8 + xcd], 1u,
                                           __ATOMIC_RELAXED, __HIP_MEMORY_SCOPE_AGENT);
      while (__hip_atomic_load(&p.ctr[bar], __ATOMIC_RELAXED, __HIP_MEMORY_SCOPE_AGENT) < (unsigned)NBLK)
        __builtin_amdgcn_s_sleep(4);
      if (cl == 0) {
        __builtin_amdgcn_fence(__ATOMIC_ACQUIRE, "agent");       // L1+L2 inv (this XCD)
        asm volatile("s_waitcnt vmcnt(0)" ::: "memory");         // inv complete
        __hip_atomic_store(&p.bdone[bar * 8 + xcd], 1u, __ATOMIC_RELAXED,
                           __HIP_MEMORY_SCOPE_AGENT);
      } else {
        while (!__hip_atomic_load(&p.bdone[bar * 8 + xcd], __ATOMIC_RELAXED,
                                  __HIP_MEMORY_SCOPE_AGENT))
          __builtin_amdgcn_s_sleep(1);
        asm volatile("buffer_inv sc0\n\ts_waitcnt vmcnt(0)" ::: "memory");  // own L1 only
      }
    }
    __syncthreads();
  };

  // out(tq) for this block's 2 batch rows, from xsrc.h1 (global, post-inv fresh)
  auto out_proj = [&](const u16* xsrc, int tq) {
    const int o = tid >> 3, ks = tid & 7;
    const int r0 = g * 256 + 2 * s;
#pragma unroll
    for (int rr = 0; rr < 2; ++rr) {
      const int r = r0 + rr;
      const u16* hp = xsrc + (size_t)r * 2048 + 1024 + ks * 128;
      const u16* wp = p.fcwb + (size_t)o * 1024 + ks * 128;
      float a = 0.f;
#pragma unroll
      for (int kk = 0; kk < 128; kk += 8) {
        bf16x8 hv = *(const bf16x8*)(hp + kk);
        bf16x8 wv = *(const bf16x8*)(wp + kk);
#pragma unroll
        for (int jj = 0; jj < 8; ++jj)
          a += bf2f(((u16*)&hv)[jj]) * bf2f(((u16*)&wv)[jj]);
      }
      a += __shfl_xor(a, 1);
      a += __shfl_xor(a, 2);
      a += __shfl_xor(a, 4);
      if (ks == 0)
        p.out[((size_t)r * SEQ + tq) * OUTD + o] = a + p.fcb[o];
    }
  };

  // one layer-phase: 4 passes of 64 batch rows; per pass: 8 double-buffered
  // X windows [64][256] (XOR-swizzled, conflict-free), 32x32x16 MFMA vs
  // register W, 8-way K-partial reduce through LDS, fused cell, h dual-publish.
  auto phase = [&](auto& wr, const u16* xsrc, u16* d1, u16* d2, int off,
                   f32x4 bb, f32x4 bxx, bool ubx, float (&cs)[4]) {
#pragma unroll
    for (int pass = 0; pass < 4; ++pass) {
      const u16* Xb = xsrc + (size_t)(g * 256 + pass * 64) * 2048;
      f32x16 acc0, acc1;
#pragma unroll
      for (int z = 0; z < 16; ++z) { acc0[z] = 0.f; acc1[z] = 0.f; }

      {  // stage window 0
        const int row = tid >> 3, seg = tid & 7, sw = (row & 7) << 4;
        const u16* src = Xb + (size_t)row * 2048 + seg * 8;
#pragma unroll
        for (int i = 0; i < 4; ++i)
          *(bf16x8*)(win0 + row * 256 + (((seg * 16 + i * 128) ^ sw) >> 1)) =
              *(const bf16x8*)(src + i * 64);
      }
      __syncthreads();
#pragma unroll
      for (int c = 0; c < 8; ++c) {
        u16* cur = (c & 1) ? win1 : win0;
        u16* nxt = (c & 1) ? win0 : win1;
        if (c < 7) {   // stage next window while computing current
          const int row = tid >> 3, seg = tid & 7, sw = (row & 7) << 4;
          const u16* src = Xb + (size_t)row * 2048 + (c + 1) * 256 + seg * 8;
#pragma unroll
          for (int i = 0; i < 4; ++i)
            *(bf16x8*)(nxt + row * 256 + (((seg * 16 + i * 128) ^ sw) >> 1)) =
                *(const bf16x8*)(src + i * 64);
        }
#pragma unroll
        for (int kfs = 0; kfs < 2; ++kfs) {
          const bf16x8 wf = wr[c * 2 + kfs];
          const int bo = wave * 64 + kfs * 32 + hh * 16;
          {
            const int row = nl;
            const bf16x8 a =
                *(const bf16x8*)(cur + row * 256 + ((bo ^ ((row & 7) << 4)) >> 1));
            acc0 = __builtin_amdgcn_mfma_f32_32x32x16_bf16(a, wf, acc0, 0, 0, 0);
          }
          {
            const int row = 32 + nl;
            const bf16x8 a =
                *(const bf16x8*)(cur + row * 256 + ((bo ^ ((row & 7) << 4)) >> 1));
            acc1 = __builtin_amdgcn_mfma_f32_32x32x16_bf16(a, wf, acc1, 0, 0, 0);
          }
        }
        __syncthreads();
      }
      // K-partials to LDS (C/D: col=lane&31, row=(reg&3)+8*(reg>>2)+4*(lane>>5))
#pragma unroll
      for (int r16 = 0; r16 < 16; ++r16) {
        const int row0 = (r16 & 3) + 8 * (r16 >> 2) + 4 * hh;
        pld[(wave * 64 + row0) * 32 + nl] = acc0[r16];
        pld[(wave * 64 + 32 + row0) * 32 + nl] = acc1[r16];
      }
      __syncthreads();
      // reduce 8 partials + cell for this lane's (row, hidden unit)
      f32x4 gs = {0.f, 0.f, 0.f, 0.f};
#pragma unroll
      for (int q = 0; q < 8; ++q) {
        const f32x4 v = *(const f32x4*)&pld[(q * 64 + cr_) * 32 + 4 * cj];
        gs[0] += v[0]; gs[1] += v[1]; gs[2] += v[2]; gs[3] += v[3];
      }
      const float gi = gs[0] + bb[0] + (ubx ? bxx[0] : 0.f);
      const float gf = gs[1] + bb[1] + (ubx ? bxx[1] : 0.f);
      const float gg = gs[2] + bb[2] + (ubx ? bxx[2] : 0.f);
      const float go = gs[3] + bb[3] + (ubx ? bxx[3] : 0.f);
      const float iv = sigf(gi), fv = sigf(gf), gv = tanh_fast(gg), ov = sigf(go);
      const float cnew = fv * cs[pass] + iv * gv;
      cs[pass] = cnew;
      const float hnew = ov * tanh_fast(cnew);
      const u16 hv = f2bf(hnew);
      const unsigned other = __shfl_xor((unsigned)hv, 1);
      if (!(tid & 1)) {   // even lane packs (jcol, jcol+1) -> one u32 store x2 dests
        const unsigned pairv = (unsigned)hv | (other << 16);
        const size_t ro = (size_t)(g * 256 + pass * 64 + cr_) * 2048 + off + jcol;
        st_dev32(d1 + ro, pairv);
        st_dev32(d2 + ro, pairv);
      }
    }
  };

  int bar = 0;
  for (int t = 0; t < SEQ; ++t) {
    u16* xap = (t & 1) ? p.xa1 : p.xa0;
    u16* xan = (t & 1) ? p.xa0 : p.xa1;
    u16* xbp = (t & 1) ? p.xb1 : p.xb0;
    u16* xbn = (t & 1) ? p.xb0 : p.xb1;
    // ---- phase A: gates0 = xap @ W0^T ; h0(t) -> xbp.h0 + xan.h0 ----
    if (t > 0) out_proj(xap, t - 1);            // out(t-1) from h1(t-1) = xap.h1
    phase(w0r, xap, xbp, xan, 0, b0, bx, t > 0, c0s);
    gbar(bar++);
    // ---- phase B: gates1 = xbp @ W1^T ; h1(t) -> xan.h1 + xbn.h1 ----
    phase(w1r, xbp, xan, xbn, 1024, b1, b1, false, c1s);
    gbar(bar++);
  }
  out_proj(p.xa0, SEQ - 1);                     // h1(255) in xa0.h1
}

// ---------------- launch ----------------

extern "C" void kernel_launch(void* const* d_in, const int* in_sizes, int n_in,
                              void* d_out, int out_size, void* d_ws, size_t ws_size,
                              hipStream_t stream) {
  const float* zs   = (const float*)d_in[0];
  const float* zk   = (const float*)d_in[1];
  const float* fiw  = (const float*)d_in[2];
  const float* fib  = (const float*)d_in[3];
  const float* Wih0 = (const float*)d_in[4];
  const float* Whh0 = (const float*)d_in[5];
  const float* bih0 = (const float*)d_in[6];
  const float* bhh0 = (const float*)d_in[7];
  const float* Wih1 = (const float*)d_in[8];
  const float* Whh1 = (const float*)d_in[9];
  const float* bih1 = (const float*)d_in[10];
  const float* bhh1 = (const float*)d_in[11];
  const float* fcw  = (const float*)d_in[12];
  const float* fcb  = (const float*)d_in[13];
  float* out = (float*)d_out;

  char* ws = (char*)d_ws;
  size_t off = 0;
  auto alloc = [&](size_t bytes) -> char* {
    char* pp = ws + off;
    off += (bytes + 255) & ~(size_t)255;
    return pp;
  };
  u16* w0f  = (u16*)alloc((size_t)NGATE * 2048 * 2);
  u16* w1f  = (u16*)alloc((size_t)NGATE * 2048 * 2);
  u16* xa0  = (u16*)alloc((size_t)BATCH * 2048 * 2);
  u16* xa1  = (u16*)alloc((size_t)BATCH * 2048 * 2);
  u16* xb0  = (u16*)alloc((size_t)BATCH * 2048 * 2);
  u16* xb1  = (u16*)alloc((size_t)BATCH * 2048 * 2);
  u16* fcwb = (u16*)alloc((size_t)OUTD * HID * 2);
  float* bias0b = (float*)alloc(NGATE * 4);
  float* bias0x = (float*)alloc(NGATE * 4);
  float* bias1  = (float*)alloc(NGATE * 4);
  unsigned* ctr    = (unsigned*)alloc((size_t)NBAR * 4);
  unsigned* bclaim = (unsigned*)alloc((size_t)NBAR * 8 * 4);
  unsigned* bdone  = (unsigned*)alloc((size_t)NBAR * 8 * 4);

  hipMemsetAsync(ctr, 0, (size_t)NBAR * 4, stream);
  hipMemsetAsync(bclaim, 0, (size_t)NBAR * 8 * 4, stream);
  hipMemsetAsync(bdone, 0, (size_t)NBAR * 8 * 4, stream);

  hipLaunchKernelGGL(k_build_w0f, dim3(NGATE), dim3(256), 0, stream, Whh0, Wih0, fcw, w0f);
  hipLaunchKernelGGL(k_build_w1f, dim3(NGATE), dim3(256), 0, stream, Wih1, Whh1, w1f);
  hipLaunchKernelGGL(k_build_bias, dim3(16), dim3(256), 0, stream,
                     bih0, bhh0, bih1, bhh1, Wih0, fcb, bias0b, bias0x, bias1);
  hipLaunchKernelGGL(k_fcwb, dim3(256), dim3(256), 0, stream, fcw, fcwb);
  hipLaunchKernelGGL(k_init, dim3(BATCH), dim3(256), 0, stream, zs, zk, fiw, fib, xa0, xb0);

  Params prm;
  prm.w0f = w0f; prm.w1f = w1f;
  prm.bias0b = bias0b; prm.bias0x = bias0x; prm.bias1 = bias1;
  prm.xa0 = xa0; prm.xa1 = xa1; prm.xb0 = xb0; prm.xb1 = xb1;
  prm.fcwb = fcwb; prm.fcb = fcb; prm.out = out;
  prm.ctr = ctr; prm.bclaim = bclaim; prm.bdone = bdone;

  hipFuncSetAttribute((const void*)k_lstm, hipFuncAttributeMaxDynamicSharedMemorySize, LDS_BYTES);
  void* args[] = { &prm };
  hipLaunchCooperativeKernel((void*)k_lstm, dim3(NBLK), dim3(NTHR), args, LDS_BYTES, stream);
}

// Round 6
// 22227.374 us; speedup vs baseline: 1.8812x; 1.4385x over previous
//
#include <hip/hip_runtime.h>
#include <hip/hip_bf16.h>
#include <hip/hip_cooperative_groups.h>

#define HID   1024
#define BATCH 512
#define SEQ   256
#define OUTD  64
#define NGATE 4096
#define NBLK  256
#define NTHR  512
#define NPH   512            // 2 phases per timestep
#define HSZ   (512 * 1024)   // elems per h parity slab [512][1024]

typedef __attribute__((ext_vector_type(8))) short bf16x8;
typedef __attribute__((ext_vector_type(4))) float f32x4;
typedef __attribute__((ext_vector_type(16))) float f32x16;
typedef unsigned short u16;
typedef unsigned long long u64;

// LDS: win0/win1 [64 rows][256 k] bf16 (32 KB each, XOR-swizzled),
//      pld [8][64][32] f32 (64 KB; first words reused as init-broadcast)
#define WIN_BYTES 32768
#define LDS_BYTES (2 * WIN_BYTES + 65536)

#define AQ __ATOMIC_RELAXED, __HIP_MEMORY_SCOPE_AGENT

__device__ __forceinline__ u16 f2bf(float v) {
  union { float f; unsigned u; } u; u.f = v;
  unsigned r = u.u + 0x7fffu + ((u.u >> 16) & 1u);
  return (u16)(r >> 16);
}
__device__ __forceinline__ float bf2f(u16 b) {
  union { unsigned u; float f; } u; u.u = ((unsigned)b) << 16;
  return u.f;
}
__device__ __forceinline__ float sigf(float x) { return 1.0f / (1.0f + __expf(-x)); }
__device__ __forceinline__ float tanh_fast(float x) {
  float ax = fabsf(x);
  float e = __expf(-2.0f * ax);
  return copysignf((1.0f - e) / (1.0f + e), x);
}

// agent-scope relaxed: write-through / read past all caches to the coherent
// point (MALL). h publish + scratch pull + final out read. (r0-r3 proven.)
__device__ __forceinline__ void st_dev32(u16* p, unsigned v) {
  __hip_atomic_store((unsigned*)p, v, AQ);
}
__device__ __forceinline__ u64 ld_dev64(const u16* p) {
  return __hip_atomic_load((const u64*)p, AQ);
}

// W frag index for the register-resident layout (r2/r3-verified).
__device__ __forceinline__ size_t fidx(int np, int k) {
  int s = np >> 5, nl = np & 31;
  int c = k >> 8;
  int kq = (k >> 5) & 7;
  int kfs = (k >> 4) & 1;
  int h = (k >> 3) & 1;
  int e = k & 7;
  int f = c * 2 + kfs;
  return ((size_t)(s * 8 + kq) * 16 + f) * 512 + (h * 32 + nl) * 8 + e;
}

// ---------------- prepass kernels (r2/r3-verified) ----------------

__global__ void k_build_w0f(const float* __restrict__ Whh0, const float* __restrict__ Wih0,
                            const float* __restrict__ fcw, u16* __restrict__ w0f) {
  int np = blockIdx.x;
  int j = np >> 2, gg = np & 3;
  int orig = gg * 1024 + j;
  int tid = threadIdx.x;
  __shared__ float wrow[64];
  if (tid < 64) wrow[tid] = Wih0[orig * 64 + tid];
  __syncthreads();
  for (int k = tid; k < 1024; k += 256) {
    w0f[fidx(np, k)] = f2bf(Whh0[(size_t)orig * 1024 + k]);
    float acc = 0.f;
#pragma unroll
    for (int o = 0; o < 64; ++o) acc += wrow[o] * fcw[o * 1024 + k];
    w0f[fidx(np, 1024 + k)] = f2bf(acc);   // folded Wih0 @ fc_out
  }
}

__global__ void k_build_w1f(const float* __restrict__ Wih1, const float* __restrict__ Whh1,
                            u16* __restrict__ w1f) {
  int np = blockIdx.x;
  int j = np >> 2, gg = np & 3;
  int orig = gg * 1024 + j;
  int tid = threadIdx.x;
  for (int k = tid; k < 1024; k += 256) {
    w1f[fidx(np, k)]        = f2bf(Wih1[(size_t)orig * 1024 + k]);
    w1f[fidx(np, 1024 + k)] = f2bf(Whh1[(size_t)orig * 1024 + k]);
  }
}

__global__ void k_build_bias(const float* bih0, const float* bhh0,
                             const float* bih1, const float* bhh1,
                             const float* Wih0, const float* fcb,
                             float* bias0b, float* bias0x, float* bias1) {
  int np = blockIdx.x * 256 + threadIdx.x;
  if (np >= NGATE) return;
  int j = np >> 2, gg = np & 3;
  int orig = gg * 1024 + j;
  bias0b[np] = bih0[orig] + bhh0[orig];
  bias1[np]  = bih1[orig] + bhh1[orig];
  float acc = 0.f;
#pragma unroll
  for (int o = 0; o < 64; ++o) acc += Wih0[orig * 64 + o] * fcb[o];
  bias0x[np] = acc;   // fc_out bias routed through W_ih0 (valid only t>=1; x(0)=0)
}

__global__ void k_fcwb(const float* __restrict__ fcw, u16* __restrict__ fcwb) {
  int idx = blockIdx.x * 256 + threadIdx.x;  // 65536
  fcwb[idx] = f2bf(fcw[idx]);
}

// writes h0_init -> xg0 parity-1 slab, h1_init -> xg1 parity-1 slab
__global__ void k_init(const float* __restrict__ zs, const float* __restrict__ zk,
                       const float* __restrict__ fiw, const float* __restrict__ fib,
                       u16* __restrict__ xg0i, u16* __restrict__ xg1i) {
  int r = blockIdx.x;
  int tid = threadIdx.x;
  __shared__ float z[256];
  if (tid < 128) z[tid] = zs[r * 128 + tid];
  else           z[tid] = zk[r * 128 + (tid - 128)];
  __syncthreads();
  for (int c = tid; c < 2048; c += 256) {
    float acc = fib[c];
    const float* w = fiw + (size_t)c * 256;
#pragma unroll 8
    for (int k = 0; k < 256; ++k) acc += z[k] * w[k];
    int l = (r >= 256) ? 1 : 0;
    int b = 2 * (r - l * 256) + (c >> 10);
    int h = c & 1023;
    u16 v = f2bf(acc);
    if (l == 0) xg0i[(size_t)b * 1024 + h] = v;
    else        xg1i[(size_t)b * 1024 + h] = v;
  }
}

// ---------------- main cooperative kernel ----------------

struct Params {
  const u16* w0f;        // frag-ordered, register-resident after prologue
  const u16* w1f;
  const float* bias0b;
  const float* bias0x;
  const float* bias1;
  u16* xg0;              // [2 parity][512][1024] h0 slabs (MALL write-through)
  u16* xg1;              // [2 parity][512][1024] h1 slabs
  u16* scr;              // [8 xcd][2 grp][256][2048] per-XCD operand scratch (L2-local)
  const u16* fcwb;       // [64][1024] bf16
  const float* fcb;
  float* out;            // [512][256][64]
  unsigned* igctr;       // init barrier counter
  unsigned* rkg;         // [8 xcd][2 grp] rank counters
  unsigned* gcnt;        // [2] group block totals
  unsigned* sctr;        // [16][NPH] fill-ready counters  (per xcd,grp)
  unsigned* axg;         // [16][NPH] gbar arrival         (per xcd,grp)
  unsigned* rls;         // [16][NPH] gbar release flags   (per xcd,grp)
  unsigned* gctr;        // [2][NPH]  gbar group-combine   (per grp)
};

__global__ __launch_bounds__(NTHR, 2)
void k_lstm(Params p) {
  extern __shared__ char smem[];
  u16* win0 = (u16*)smem;                       // [64][256] bf16, swizzled
  u16* win1 = (u16*)(smem + WIN_BYTES);
  float* pld = (float*)(smem + 2 * WIN_BYTES);  // [8 kq][64 m][32 n] f32
  volatile unsigned* bc = (volatile unsigned*)pld;  // init-time alias (safe: pld
                                                    // first written much later)

  const int blk = blockIdx.x, tid = threadIdx.x;
  const int lane = tid & 63, wave = tid >> 6;   // wave id = kq (K-slice)
  const int x8 = blk & 7;
  const int g = x8 >> 2;                        // batch group 0..1
  const int s = (blk >> 3) * 4 + (x8 & 3);      // gate-slab 0..127 (np 32s..32s+32)
  const int nl = lane & 31, hh = lane >> 5;

  // physical XCD id (r3-proven): s_getreg(HW_REG_XCC_ID) -> 0..7
  unsigned xcd;
  asm("s_getreg_b32 %0, hwreg(HW_REG_XCC_ID, 0, 32)" : "=s"(xcd));
  xcd &= 7;

  // ---- rank discovery + one global init barrier (agent atomics only) ----
  if (tid == 0) {
    unsigned rg = __hip_atomic_fetch_add(&p.rkg[xcd * 2 + g], 1u, AQ);
    __hip_atomic_fetch_add(&p.gcnt[g], 1u, AQ);
    __hip_atomic_fetch_add(p.igctr, 1u, AQ);
    while (__hip_atomic_load(p.igctr, AQ) < (unsigned)NBLK)
      __builtin_amdgcn_s_sleep(2);
    bc[0] = rg;
    bc[1] = __hip_atomic_load(&p.rkg[xcd * 2 + g], AQ);
    bc[2] = __hip_atomic_load(&p.gcnt[g], AQ);
  }
  __syncthreads();
  const unsigned rg_   = bc[0];   // my rank within (xcd, group)
  const unsigned ng_   = bc[1];   // blocks of my group on this XCD (>=1)
  const unsigned ngrp_ = bc[2];   // total blocks of my group
  const bool lead = (rg_ == 0);   // unique leader per (xcd, group)
  __syncthreads();

  // ---- load W into registers: zero W fetch for all 512 phases (r2-proven) ----
  bf16x8 w0r[16], w1r[16];
  {
    const u16* W0p = p.w0f + (size_t)(s * 8 + wave) * 8192 + (hh * 32 + nl) * 8;
    const u16* W1p = p.w1f + (size_t)(s * 8 + wave) * 8192 + (hh * 32 + nl) * 8;
#pragma unroll
    for (int f = 0; f < 16; ++f) {
      w0r[f] = *(const bf16x8*)(W0p + f * 512);
      w1r[f] = *(const bf16x8*)(W1p + f * 512);
    }
  }

  // cell assignment: one (row-in-pass, hidden-unit) per lane
  const int cr_ = tid >> 3, cj = tid & 7;
  const int npb = s * 32 + 4 * cj;
  const f32x4 b0 = *(const f32x4*)&p.bias0b[npb];
  const f32x4 bx = *(const f32x4*)&p.bias0x[npb];
  const f32x4 b1 = *(const f32x4*)&p.bias1[npb];
  const int jcol = s * 8 + cj;                  // hidden-unit column [0,1024)

  float c0s[4] = {0, 0, 0, 0}, c1s[4] = {0, 0, 0, 0};

  u16* scrg = p.scr + (size_t)(xcd * 2 + g) * 256 * 2048;  // (XCD,group) scratch

  // ---- group-scoped hierarchical barrier: NO sc1 fence anywhere ----
  auto gbar = [&](int ph) {
    __syncthreads();   // vmcnt(0) drain -> h write-through stores durable
    if (tid == 0) {
      unsigned* ax = &p.axg[(xcd * 2 + g) * NPH + ph];
      __hip_atomic_fetch_add(ax, 1u, AQ);
      if (lead) {
        while (__hip_atomic_load(ax, AQ) < ng_) __builtin_amdgcn_s_sleep(1);
        unsigned* gc = &p.gctr[g * NPH + ph];
        __hip_atomic_fetch_add(gc, ng_, AQ);
        while (__hip_atomic_load(gc, AQ) < ngrp_) __builtin_amdgcn_s_sleep(1);
        __hip_atomic_store(&p.rls[(xcd * 2 + g) * NPH + ph], 1u, AQ);
      } else {
        while (!__hip_atomic_load(&p.rls[(xcd * 2 + g) * NPH + ph], AQ))
          __builtin_amdgcn_s_sleep(1);
      }
    }
    __syncthreads();
  };

  // XCD-local fill-ready barrier; ends with private-L1 flash (r3-proven cheap)
  auto lbar = [&](int ph) {
    __syncthreads();   // drain fill stores into own L2
    if (tid == 0) {
      unsigned* c = &p.sctr[(xcd * 2 + g) * NPH + ph];
      __hip_atomic_fetch_add(c, 1u, AQ);
      while (__hip_atomic_load(c, AQ) < ng_) __builtin_amdgcn_s_sleep(1);
    }
    __syncthreads();
    asm volatile("buffer_inv sc0\n\ts_waitcnt vmcnt(0)" ::: "memory");
  };

  // bulk-pull my group's operand into this XCD's scratch: agent loads (MALL)
  // -> plain stores (dirty only in own L2).
  auto fill = [&](const u16* lo, const u16* hi, bool zhi, bool dohi) {
    const int c = tid;
    for (int r = (int)rg_; r < 256; r += (int)ng_) {
      u16* drow = scrg + (size_t)r * 2048;
      const size_t grow = (size_t)(g * 256 + r) * 1024;
      if (c < 256) {
        *(u64*)(drow + c * 4) = ld_dev64(lo + grow + c * 4);
      } else if (dohi) {
        *(u64*)(drow + 1024 + (c - 256) * 4) =
            zhi ? 0ull : ld_dev64(hi + grow + (c - 256) * 4);
      }
    }
  };

  // out(tq) for this block's 2 batch rows, h1(tq) = scratch cols [1024,2048)
  auto out_proj_s = [&](int tq) {
    const int o = tid >> 3, ks = tid & 7;
#pragma unroll
    for (int rr = 0; rr < 2; ++rr) {
      const int rl = 2 * s + rr;
      const u16* hp = scrg + (size_t)rl * 2048 + 1024 + ks * 128;
      const u16* wp = p.fcwb + (size_t)o * 1024 + ks * 128;
      float a = 0.f;
#pragma unroll
      for (int kk = 0; kk < 128; kk += 8) {
        bf16x8 hv = *(const bf16x8*)(hp + kk);
        bf16x8 wv = *(const bf16x8*)(wp + kk);
#pragma unroll
        for (int jj = 0; jj < 8; ++jj)
          a += bf2f(((u16*)&hv)[jj]) * bf2f(((u16*)&wv)[jj]);
      }
      a += __shfl_xor(a, 1);
      a += __shfl_xor(a, 2);
      a += __shfl_xor(a, 4);
      if (ks == 0)
        p.out[((size_t)(g * 256 + rl) * SEQ + tq) * OUTD + o] = a + p.fcb[o];
    }
  };

  // one layer-phase on the XCD scratch (r2/r3-verified core)
  auto phase = [&](bf16x8 (&wr)[16], u16* dst,
                   const f32x4& bb, const f32x4& bxx, bool ubx, float (&cs)[4]) {
#pragma unroll
    for (int pass = 0; pass < 4; ++pass) {
      const u16* Xb = scrg + (size_t)(pass * 64) * 2048;
      f32x16 acc0, acc1;
#pragma unroll
      for (int z = 0; z < 16; ++z) { acc0[z] = 0.f; acc1[z] = 0.f; }

      {  // stage window 0
        const int row = tid >> 3, seg = tid & 7, sw = (row & 7) << 4;
        const u16* src = Xb + (size_t)row * 2048 + seg * 8;
#pragma unroll
        for (int i = 0; i < 4; ++i)
          *(bf16x8*)(win0 + row * 256 + (((seg * 16 + i * 128) ^ sw) >> 1)) =
              *(const bf16x8*)(src + i * 64);
      }
      __syncthreads();
#pragma unroll
      for (int c = 0; c < 8; ++c) {
        u16* cur = (c & 1) ? win1 : win0;
        u16* nxt = (c & 1) ? win0 : win1;
        if (c < 7) {   // stage next window while computing current
          const int row = tid >> 3, seg = tid & 7, sw = (row & 7) << 4;
          const u16* src = Xb + (size_t)row * 2048 + (c + 1) * 256 + seg * 8;
#pragma unroll
          for (int i = 0; i < 4; ++i)
            *(bf16x8*)(nxt + row * 256 + (((seg * 16 + i * 128) ^ sw) >> 1)) =
                *(const bf16x8*)(src + i * 64);
        }
#pragma unroll
        for (int kfs = 0; kfs < 2; ++kfs) {
          const bf16x8 wf = wr[c * 2 + kfs];
          const int bo = wave * 64 + kfs * 32 + hh * 16;
          {
            const int row = nl;
            const bf16x8 a =
                *(const bf16x8*)(cur + row * 256 + ((bo ^ ((row & 7) << 4)) >> 1));
            acc0 = __builtin_amdgcn_mfma_f32_32x32x16_bf16(a, wf, acc0, 0, 0, 0);
          }
          {
            const int row = 32 + nl;
            const bf16x8 a =
                *(const bf16x8*)(cur + row * 256 + ((bo ^ ((row & 7) << 4)) >> 1));
            acc1 = __builtin_amdgcn_mfma_f32_32x32x16_bf16(a, wf, acc1, 0, 0, 0);
          }
        }
        __syncthreads();
      }
      // K-partials to LDS (C/D: col=lane&31, row=(reg&3)+8*(reg>>2)+4*(lane>>5))
#pragma unroll
      for (int r16 = 0; r16 < 16; ++r16) {
        const int row0 = (r16 & 3) + 8 * (r16 >> 2) + 4 * hh;
        pld[(wave * 64 + row0) * 32 + nl] = acc0[r16];
        pld[(wave * 64 + 32 + row0) * 32 + nl] = acc1[r16];
      }
      __syncthreads();
      // reduce 8 partials + cell for this lane's (row, hidden unit)
      f32x4 gs = {0.f, 0.f, 0.f, 0.f};
#pragma unroll
      for (int q = 0; q < 8; ++q) {
        const f32x4 v = *(const f32x4*)&pld[(q * 64 + cr_) * 32 + 4 * cj];
        gs[0] += v[0]; gs[1] += v[1]; gs[2] += v[2]; gs[3] += v[3];
      }
      const float gi = gs[0] + bb[0] + (ubx ? bxx[0] : 0.f);
      const float gf = gs[1] + bb[1] + (ubx ? bxx[1] : 0.f);
      const float gg = gs[2] + bb[2] + (ubx ? bxx[2] : 0.f);
      const float go = gs[3] + bb[3] + (ubx ? bxx[3] : 0.f);
      const float iv = sigf(gi), fv = sigf(gf), gv = tanh_fast(gg), ov = sigf(go);
      const float cnew = fv * cs[pass] + iv * gv;
      cs[pass] = cnew;
      const float hnew = ov * tanh_fast(cnew);
      const u16 hv = f2bf(hnew);
      const unsigned other = __shfl_xor((unsigned)hv, 1);
      if (!(tid & 1)) {   // even lane packs (jcol, jcol+1) -> one u32 write-through
        const unsigned pairv = (unsigned)hv | (other << 16);
        st_dev32(dst + (size_t)(g * 256 + pass * 64 + cr_) * 1024 + jcol, pairv);
      }
      __syncthreads();
    }
  };

  for (int t = 0; t < SEQ; ++t) {
    const int pp = t & 1, pq = pp ^ 1;
    const int ph = 2 * t;
    // ---- phase A: operand [h0(t-1) | h1(t-1)] (hi zero at t=0: x(0)=0) ----
    fill(p.xg0 + (size_t)pq * HSZ, p.xg1 + (size_t)pq * HSZ, t == 0, true);
    lbar(ph);
    if (t > 0) out_proj_s(t - 1);                 // out(t-1) from h1(t-1) in scratch
    phase(w0r, p.xg0 + (size_t)pp * HSZ, b0, bx, t > 0, c0s);   // h0(t)
    gbar(ph);
    // ---- phase B: operand [h0(t) | h1(t-1)] ----
    // BUGFIX (r5): at t=0 the hi half kept from fill A is ZERO (x(0)-zeroing),
    // but layer 1 needs h1(-1) = h1_init -> re-pull hi at t==0 only.
    fill(p.xg0 + (size_t)pp * HSZ, p.xg1 + (size_t)pq * HSZ, false, t == 0);
    lbar(ph + 1);
    phase(w1r, p.xg1 + (size_t)pp * HSZ, b1, b1, false, c1s);   // h1(t)
    gbar(ph + 1);
  }
  // final out(SEQ-1): h1(255) in xg1 parity 1, via agent loads
  {
    const u16* h1b = p.xg1 + (size_t)((SEQ - 1) & 1) * HSZ;
    const int o = tid >> 3, ks = tid & 7;
#pragma unroll
    for (int rr = 0; rr < 2; ++rr) {
      const int r = g * 256 + 2 * s + rr;
      const u16* hp = h1b + (size_t)r * 1024 + ks * 128;
      const u16* wp = p.fcwb + (size_t)o * 1024 + ks * 128;
      float a = 0.f;
      for (int kk = 0; kk < 128; kk += 4) {
        u64 hv = ld_dev64(hp + kk);
        a += bf2f((u16)hv)         * bf2f(wp[kk]);
        a += bf2f((u16)(hv >> 16)) * bf2f(wp[kk + 1]);
        a += bf2f((u16)(hv >> 32)) * bf2f(wp[kk + 2]);
        a += bf2f((u16)(hv >> 48)) * bf2f(wp[kk + 3]);
      }
      a += __shfl_xor(a, 1);
      a += __shfl_xor(a, 2);
      a += __shfl_xor(a, 4);
      if (ks == 0)
        p.out[((size_t)r * SEQ + (SEQ - 1)) * OUTD + o] = a + p.fcb[o];
    }
  }
}

// ---------------- launch ----------------

extern "C" void kernel_launch(void* const* d_in, const int* in_sizes, int n_in,
                              void* d_out, int out_size, void* d_ws, size_t ws_size,
                              hipStream_t stream) {
  const float* zs   = (const float*)d_in[0];
  const float* zk   = (const float*)d_in[1];
  const float* fiw  = (const float*)d_in[2];
  const float* fib  = (const float*)d_in[3];
  const float* Wih0 = (const float*)d_in[4];
  const float* Whh0 = (const float*)d_in[5];
  const float* bih0 = (const float*)d_in[6];
  const float* bhh0 = (const float*)d_in[7];
  const float* Wih1 = (const float*)d_in[8];
  const float* Whh1 = (const float*)d_in[9];
  const float* bih1 = (const float*)d_in[10];
  const float* bhh1 = (const float*)d_in[11];
  const float* fcw  = (const float*)d_in[12];
  const float* fcb  = (const float*)d_in[13];
  float* out = (float*)d_out;

  char* ws = (char*)d_ws;
  size_t off = 0;
  auto alloc = [&](size_t bytes) -> char* {
    char* pp = ws + off;
    off += (bytes + 255) & ~(size_t)255;
    return pp;
  };
  u16* w0f  = (u16*)alloc((size_t)NGATE * 2048 * 2);        // 16 MB
  u16* w1f  = (u16*)alloc((size_t)NGATE * 2048 * 2);        // 16 MB
  u16* xg0  = (u16*)alloc((size_t)2 * HSZ * 2);             // 2 MB
  u16* xg1  = (u16*)alloc((size_t)2 * HSZ * 2);             // 2 MB
  u16* scr  = (u16*)alloc((size_t)8 * 2 * 256 * 2048 * 2);  // 16 MB
  u16* fcwb = (u16*)alloc((size_t)OUTD * HID * 2);
  float* bias0b = (float*)alloc(NGATE * 4);
  float* bias0x = (float*)alloc(NGATE * 4);
  float* bias1  = (float*)alloc(NGATE * 4);
  unsigned* igctr = (unsigned*)alloc(256);
  unsigned* rkg   = (unsigned*)alloc(16 * 4);
  unsigned* gcnt  = (unsigned*)alloc(2 * 4);
  unsigned* sctr  = (unsigned*)alloc((size_t)16 * NPH * 4);
  unsigned* axg   = (unsigned*)alloc((size_t)16 * NPH * 4);
  unsigned* rls   = (unsigned*)alloc((size_t)16 * NPH * 4);
  unsigned* gctr  = (unsigned*)alloc((size_t)2 * NPH * 4);

  hipMemsetAsync(igctr, 0, 256, stream);
  hipMemsetAsync(rkg, 0, 16 * 4, stream);
  hipMemsetAsync(gcnt, 0, 2 * 4, stream);
  hipMemsetAsync(sctr, 0, (size_t)16 * NPH * 4, stream);
  hipMemsetAsync(axg, 0, (size_t)16 * NPH * 4, stream);
  hipMemsetAsync(rls, 0, (size_t)16 * NPH * 4, stream);
  hipMemsetAsync(gctr, 0, (size_t)2 * NPH * 4, stream);

  hipLaunchKernelGGL(k_build_w0f, dim3(NGATE), dim3(256), 0, stream, Whh0, Wih0, fcw, w0f);
  hipLaunchKernelGGL(k_build_w1f, dim3(NGATE), dim3(256), 0, stream, Wih1, Whh1, w1f);
  hipLaunchKernelGGL(k_build_bias, dim3(16), dim3(256), 0, stream,
                     bih0, bhh0, bih1, bhh1, Wih0, fcb, bias0b, bias0x, bias1);
  hipLaunchKernelGGL(k_fcwb, dim3(256), dim3(256), 0, stream, fcw, fcwb);
  hipLaunchKernelGGL(k_init, dim3(BATCH), dim3(256), 0, stream, zs, zk, fiw, fib,
                     xg0 + (size_t)1 * HSZ, xg1 + (size_t)1 * HSZ);

  Params prm;
  prm.w0f = w0f; prm.w1f = w1f;
  prm.bias0b = bias0b; prm.bias0x = bias0x; prm.bias1 = bias1;
  prm.xg0 = xg0; prm.xg1 = xg1; prm.scr = scr;
  prm.fcwb = fcwb; prm.fcb = fcb; prm.out = out;
  prm.igctr = igctr; prm.rkg = rkg; prm.gcnt = gcnt;
  prm.sctr = sctr; prm.axg = axg; prm.rls = rls; prm.gctr = gctr;

  hipFuncSetAttribute((const void*)k_lstm, hipFuncAttributeMaxDynamicSharedMemorySize, LDS_BYTES);
  void* args[] = { &prm };
  hipLaunchCooperativeKernel((void*)k_lstm, dim3(NBLK), dim3(NTHR), args, LDS_BYTES, stream);
}